// Round 9
// baseline (262.816 us; speedup 1.0000x reference)
//
#include <hip/hip_runtime.h>
#include <math.h>

#define IMG_H 512
#define IMG_W 512
#define IPB   4            // images per block (software-pipelined)
#define SAB_S 56           // halo stride in halves (112 B rows, 16B-aligned)
#define HT_S  56           // hT stride in halves

typedef _Float16 f16x4 __attribute__((ext_vector_type(4)));
typedef _Float16 f16x8 __attribute__((ext_vector_type(8)));
typedef float    f32x4 __attribute__((ext_vector_type(4)));

// LDS-only barrier: drain lgkmcnt, leave global loads (vmcnt) in flight.
__device__ __forceinline__ void lds_barrier() {
    __asm__ volatile("" ::: "memory");
    __builtin_amdgcn_s_waitcnt(0xC07F);   // vmcnt=63, expcnt=7, lgkmcnt=0
    __builtin_amdgcn_s_barrier();
    __asm__ volatile("" ::: "memory");
}

__device__ __forceinline__ f16x8 pack8(const float4& a, const float4& b) {
    return f16x8{(_Float16)a.x, (_Float16)a.y, (_Float16)a.z, (_Float16)a.w,
                 (_Float16)b.x, (_Float16)b.y, (_Float16)b.z, (_Float16)b.w};
}

// Banded Gaussian fragments. Bw (which=0): B[k][n]=w[k-n-3]; A2w (which=1): A[m][k]=w[k-m]
__device__ __forceinline__ f16x8 build_frag(int which, int l)
{
    const int lln = l & 15, llg = l >> 4;
    f16x8 f;
    #pragma unroll
    for (int j = 0; j < 8; ++j) {
        int idx = llg * 8 + j - lln - (which ? 0 : 3);
        float d = (float)(idx - 5);
        float v = 0.26601173f * exp2f(-d * d * 0.32059889f);
        f[j] = (_Float16)(((unsigned)idx <= 10u) ? v : 0.0f);
    }
    return f;
}

__global__ __launch_bounds__(256, 4)
void ssim_fused(const float* __restrict__ pred, const float* __restrict__ targ,
                float* __restrict__ out, double* __restrict__ acc,
                unsigned* __restrict__ counter, int n_img, int nblk, double inv_n)
{
    __shared__ _Float16 sAB[2][48][SAB_S];   // p, t halo (f16)
    __shared__ _Float16 hT[5][32][HT_S];     // [q][out_col][halo_row 0..47]
    __shared__ float red[4];

    const int tid  = threadIdx.x;
    const int lane = tid & 63, wave = tid >> 6;
    const int ln   = lane & 15, lg = lane >> 4;
    const int tx = blockIdx.x, ty = blockIdx.y;

    // stage-A item ownership: item0 = tid (always), item1 = tid+256 (tid<32)
    const int r0 = tid / 6,        g0 = tid % 6;
    const bool has1 = (tid < 32);
    const int r1 = (tid + 256) / 6, g1 = (tid + 256) % 6;

    const int gr0 = ty * 32 - 5;       // halo row 0 (global)
    const int wo  = tx * 32 - 8;       // halo col 0 (global), 32B-aligned groups
    auto valid = [&](int r, int g) {
        int gr = gr0 + r;
        return gr >= 0 && gr < IMG_H &&
               !(tx == 0 && g == 0) && !(tx == 15 && g == 5);
    };
    const bool v0 = valid(r0, g0);
    const bool v1 = has1 && valid(r1, g1);
    const size_t off0 = (size_t)(gr0 + r0) * IMG_W + (wo + 8 * g0);
    const size_t off1 = (size_t)(gr0 + r1) * IMG_W + (wo + 8 * g1);

    const f16x8 Bw  = build_frag(0, lane);
    const f16x8 A2w = build_frag(1, lane);
    const f32x4 z = {0.f, 0.f, 0.f, 0.f};

    const int imgBase = blockIdx.z * IPB;
    float lsum = 0.f;

    // ---- preload image imgBase ----
    float4 P0a{0,0,0,0}, P0b{0,0,0,0}, T0a{0,0,0,0}, T0b{0,0,0,0};
    float4 P1a{0,0,0,0}, P1b{0,0,0,0}, T1a{0,0,0,0}, T1b{0,0,0,0};
    if (imgBase < n_img) {
        const size_t ib = (size_t)imgBase * (IMG_H * IMG_W);
        if (v0) {
            const float* bp = pred + ib + off0; const float* bt = targ + ib + off0;
            P0a = ((const float4*)bp)[0]; P0b = ((const float4*)bp)[1];
            T0a = ((const float4*)bt)[0]; T0b = ((const float4*)bt)[1];
        }
        if (v1) {
            const float* bp = pred + ib + off1; const float* bt = targ + ib + off1;
            P1a = ((const float4*)bp)[0]; P1b = ((const float4*)bp)[1];
            T1a = ((const float4*)bt)[0]; T1b = ((const float4*)bt)[1];
        }
    }

    #pragma unroll
    for (int it = 0; it < IPB; ++it) {
        const bool live = (imgBase + it < n_img);

        // ---- Stage A: pack current regs -> sAB (f16) ----
        *(f16x8*)&sAB[0][r0][8 * g0] = pack8(P0a, P0b);
        *(f16x8*)&sAB[1][r0][8 * g0] = pack8(T0a, T0b);
        if (has1) {
            *(f16x8*)&sAB[0][r1][8 * g1] = pack8(P1a, P1b);
            *(f16x8*)&sAB[1][r1][8 * g1] = pack8(T1a, T1b);
        }

        // ---- issue next image's loads (regs dead after pack; full B+C of slack) ----
        if (it + 1 < IPB) {
            const int img2 = imgBase + it + 1;
            P0a = {0,0,0,0}; P0b = {0,0,0,0}; T0a = {0,0,0,0}; T0b = {0,0,0,0};
            P1a = {0,0,0,0}; P1b = {0,0,0,0}; T1a = {0,0,0,0}; T1b = {0,0,0,0};
            if (img2 < n_img) {
                const size_t ib = (size_t)img2 * (IMG_H * IMG_W);
                if (v0) {
                    const float* bp = pred + ib + off0; const float* bt = targ + ib + off0;
                    P0a = ((const float4*)bp)[0]; P0b = ((const float4*)bp)[1];
                    T0a = ((const float4*)bt)[0]; T0b = ((const float4*)bt)[1];
                }
                if (v1) {
                    const float* bp = pred + ib + off1; const float* bt = targ + ib + off1;
                    P1a = ((const float4*)bp)[0]; P1b = ((const float4*)bp)[1];
                    T1a = ((const float4*)bt)[0]; T1b = ((const float4*)bt)[1];
                }
            }
        }
        lds_barrier();

        // ---- Stage B: horizontal conv via MFMA; pp/tt/pt packed on the fly ----
        auto do_tile = [&](int tt) {
            const int rt = tt >> 1, ct = tt & 1;
            const int rowbase = rt * 16;                 // {0,16,32}
            f16x8 pa = *(const f16x8*)&sAB[0][rowbase + ln][ct * 16 + lg * 8];
            f16x8 ta = *(const f16x8*)&sAB[1][rowbase + ln][ct * 16 + lg * 8];
            f16x8 fq[5];
            fq[0] = pa; fq[1] = ta;
            fq[2] = pa * pa; fq[3] = ta * ta; fq[4] = pa * ta;
            const int ocol = ct * 16 + ln;
            const int orow = rowbase + lg * 4;           // 8B-aligned
            #pragma unroll
            for (int q = 0; q < 5; ++q) {
                f32x4 d = __builtin_amdgcn_mfma_f32_16x16x32_f16(fq[q], Bw, z, 0, 0, 0);
                *(f16x4*)&hT[q][ocol][orow] =
                    f16x4{(_Float16)d[0], (_Float16)d[1], (_Float16)d[2], (_Float16)d[3]};
            }
        };
        do_tile(wave);
        if (wave < 2) do_tile(wave + 4);
        lds_barrier();

        // ---- Stage C: vertical conv via MFMA + SSIM ----
        {
            const int ctv = wave & 1, rtv = wave >> 1;
            const int ocol  = ctv * 16 + ln;
            const int rbase = rtv * 16 + lg * 8;         // 16B-aligned
            f32x4 accq[5];
            #pragma unroll
            for (int q = 0; q < 5; ++q) {
                f16x8 b = *(const f16x8*)&hT[q][ocol][rbase];
                accq[q] = __builtin_amdgcn_mfma_f32_16x16x32_f16(A2w, b, z, 0, 0, 0);
            }
            if (live) {
                const float C1 = 1e-4f, C2 = 9e-4f;
                #pragma unroll
                for (int r = 0; r < 4; ++r) {
                    float mp = accq[0][r], mt = accq[1][r];
                    float vp = accq[2][r] - mp * mp;
                    float vt = accq[3][r] - mt * mt;
                    float cv = accq[4][r] - mp * mt;
                    float num = (2.f * mp * mt + C1) * (2.f * cv + C2);
                    float den = (mp * mp + mt * mt + C1) * (vp + vt + C2);
                    lsum = fmaf(num, __builtin_amdgcn_rcpf(den), lsum);
                }
            }
        }
    }

    // ---- block reduce -> device atomic; last block finalizes ----
    #pragma unroll
    for (int off = 32; off > 0; off >>= 1)
        lsum += __shfl_down(lsum, off, 64);
    if (lane == 0) red[wave] = lsum;
    __syncthreads();
    if (tid == 0) {
        double bs = (double)red[0] + (double)red[1] + (double)red[2] + (double)red[3];
        atomicAdd(acc, bs);
        __threadfence();
        unsigned old = atomicAdd(counter, 1u);
        if (old == (unsigned)(nblk - 1)) {
            double tot = atomicAdd(acc, 0.0);   // coherent read at L2 point
            out[0] = (float)(1.0 - tot * inv_n);
        }
    }
}

extern "C" void kernel_launch(void* const* d_in, const int* in_sizes, int n_in,
                              void* d_out, int out_size, void* d_ws, size_t ws_size,
                              hipStream_t stream)
{
    const float* pred = (const float*)d_in[0];
    const float* targ = (const float*)d_in[1];
    float* out = (float*)d_out;

    const long long total = (long long)in_sizes[0];       // 16*3*512*512
    const int n_img = (int)(total / (IMG_H * IMG_W));     // 48 planes
    const int nz = (n_img + IPB - 1) / IPB;               // 12
    dim3 grid(IMG_W / 32, IMG_H / 32, nz);
    const int nblk = grid.x * grid.y * grid.z;
    const double inv_n = 1.0 / (double)total;

    double*   acc     = (double*)d_ws;
    unsigned* counter = (unsigned*)((char*)d_ws + 8);

    hipMemsetAsync(d_ws, 0, 16, stream);
    hipLaunchKernelGGL(ssim_fused, grid, dim3(256), 0, stream,
                       pred, targ, out, acc, counter, n_img, nblk, inv_n);
}

// Round 10
// 140.305 us; speedup vs baseline: 1.8732x; 1.8732x over previous
//
#include <hip/hip_runtime.h>
#include <math.h>

#define IMG_H 512
#define IMG_W 512
#define NSLOT 64
#define SAB_S 56      // halo stride in halves: 112 B rows, 16B-aligned
#define HT_S  56      // hT stride in halves

typedef _Float16 f16x4 __attribute__((ext_vector_type(4)));
typedef _Float16 f16x8 __attribute__((ext_vector_type(8)));
typedef float    f32x4 __attribute__((ext_vector_type(4)));

// Banded Gaussian fragments. Bw (which=0): B[k][n]=w[k-n-3]; A2w (which=1): A[m][k]=w[k-m]
__device__ __forceinline__ f16x8 build_frag(int which, int l)
{
    const int lln = l & 15, llg = l >> 4;
    f16x8 f;
    #pragma unroll
    for (int j = 0; j < 8; ++j) {
        int idx = llg * 8 + j - lln - (which ? 0 : 3);
        float d = (float)(idx - 5);
        float v = 0.26601173f * exp2f(-d * d * 0.32059889f);
        f[j] = (_Float16)(((unsigned)idx <= 10u) ? v : 0.0f);
    }
    return f;
}

__global__ __launch_bounds__(256, 6)
void ssim_main(const float* __restrict__ pred, const float* __restrict__ targ,
               float* __restrict__ partial, double* __restrict__ acc, int mode)
{
    __shared__ _Float16 sAB[2][48][SAB_S];   // [0]=s=p+t, [1]=d=p-t (f16)
    __shared__ _Float16 hT[4][32][HT_S];     // [q][out_col][halo_row 0..47]

    const int tid  = threadIdx.x;
    const int lane = tid & 63, wave = tid >> 6;
    const int ln   = lane & 15, lg = lane >> 4;

    const int tx = blockIdx.x, ty = blockIdx.y, img = blockIdx.z;
    const float* __restrict__ p = pred + (size_t)img * (IMG_H * IMG_W);
    const float* __restrict__ t = targ + (size_t)img * (IMG_H * IMG_W);
    const int gr0 = ty * 32 - 5;       // halo row 0 (global)
    const int wo  = tx * 32 - 8;       // halo col 0 (global), 32B-aligned groups
    // output col n uses halo cols n+3 .. n+13 (band offset -3)

    const f16x8 Bw  = build_frag(0, lane);
    const f16x8 A2w = build_frag(1, lane);
    const f32x4 z = {0.f, 0.f, 0.f, 0.f};

    // ---- Stage A: load p,t; stage s=p+t, d=p-t as f16 ----
    // 48 rows x 6 groups of 8 cols = 288 items
    for (int i = tid; i < 48 * 6; i += 256) {
        const int r = i / 6, g = i - 6 * r;
        const int gr = gr0 + r;
        const bool in = (gr >= 0) && (gr < IMG_H) &&
                        !(tx == 0 && g == 0) && !(tx == 15 && g == 5);
        float4 p0 = {0,0,0,0}, p1 = {0,0,0,0}, t0 = {0,0,0,0}, t1 = {0,0,0,0};
        if (in) {
            const float* bp = p + (size_t)gr * IMG_W + (wo + 8 * g);
            const float* bt = t + (size_t)gr * IMG_W + (wo + 8 * g);
            p0 = ((const float4*)bp)[0]; p1 = ((const float4*)bp)[1];
            t0 = ((const float4*)bt)[0]; t1 = ((const float4*)bt)[1];
        }
        *(f16x8*)&sAB[0][r][8 * g] = f16x8{
            (_Float16)(p0.x + t0.x), (_Float16)(p0.y + t0.y),
            (_Float16)(p0.z + t0.z), (_Float16)(p0.w + t0.w),
            (_Float16)(p1.x + t1.x), (_Float16)(p1.y + t1.y),
            (_Float16)(p1.z + t1.z), (_Float16)(p1.w + t1.w)};
        *(f16x8*)&sAB[1][r][8 * g] = f16x8{
            (_Float16)(p0.x - t0.x), (_Float16)(p0.y - t0.y),
            (_Float16)(p0.z - t0.z), (_Float16)(p0.w - t0.w),
            (_Float16)(p1.x - t1.x), (_Float16)(p1.y - t1.y),
            (_Float16)(p1.z - t1.z), (_Float16)(p1.w - t1.w)};
    }
    __syncthreads();

    // ---- Stage B: horizontal conv via MFMA on {s, d, s^2, d^2} ----
    // 6 tiles: rowbase in {0,16,32} x ct in {0,1}
    auto do_tile = [&](int tt) {
        const int rt = tt >> 1, ct = tt & 1;
        const int rowbase = rt * 16;
        f16x8 s8 = *(const f16x8*)&sAB[0][rowbase + ln][ct * 16 + lg * 8];
        f16x8 d8 = *(const f16x8*)&sAB[1][rowbase + ln][ct * 16 + lg * 8];
        f16x8 fq[4];
        fq[0] = s8; fq[1] = d8;
        fq[2] = s8 * s8; fq[3] = d8 * d8;
        const int ocol = ct * 16 + ln;
        const int orow = rowbase + lg * 4;          // 8B-aligned b64 writes
        #pragma unroll
        for (int q = 0; q < 4; ++q) {
            f32x4 dd = __builtin_amdgcn_mfma_f32_16x16x32_f16(fq[q], Bw, z, 0, 0, 0);
            *(f16x4*)&hT[q][ocol][orow] =
                f16x4{(_Float16)dd[0], (_Float16)dd[1], (_Float16)dd[2], (_Float16)dd[3]};
        }
    };
    do_tile(wave);
    if (wave < 2) do_tile(wave + 4);
    __syncthreads();

    // ---- Stage C: vertical conv via MFMA (weights as A) + SSIM ----
    float lsum = 0.f;
    {
        const int ctv = wave & 1, rtv = wave >> 1;   // one 16x16 output tile per wave
        const int ocol  = ctv * 16 + ln;
        const int rbase = rtv * 16 + lg * 8;         // 16B-aligned b128 reads
        f32x4 accq[4];
        #pragma unroll
        for (int q = 0; q < 4; ++q) {
            f16x8 b = *(const f16x8*)&hT[q][ocol][rbase];
            accq[q] = __builtin_amdgcn_mfma_f32_16x16x32_f16(A2w, b, z, 0, 0, 0);
        }
        // F1=conv(s)=mp+mt, F2=conv(d)=mp-mt, F3=conv(s^2), F4=conv(d^2)
        const float C1 = 1e-4f, C2 = 9e-4f;
        #pragma unroll
        for (int r = 0; r < 4; ++r) {
            float F1 = accq[0][r], F2 = accq[1][r];
            float F3 = accq[2][r], F4 = accq[3][r];
            float a = F1 * F1, b = F2 * F2;
            float mpmt2 = 0.5f * (a - b);            // 2*mp*mt
            float msq   = 0.5f * (a + b);            // mp^2 + mt^2
            float cpt2  = 0.5f * (F3 - F4) - mpmt2;  // 2*sigma_pt
            float vsum  = 0.5f * (F3 + F4) - msq;    // sigma_p^2 + sigma_t^2
            float num = (mpmt2 + C1) * (cpt2 + C2);
            float den = (msq + C1) * (vsum + C2);
            lsum = fmaf(num, __builtin_amdgcn_rcpf(den), lsum);
        }
    }

    // ---- wave reduce -> per-wave slot (mode 0) or atomic (mode 1); no end barrier ----
    #pragma unroll
    for (int off = 32; off > 0; off >>= 1)
        lsum += __shfl_down(lsum, off, 64);
    if (lane == 0) {
        const int bid = (blockIdx.z * gridDim.y + blockIdx.y) * gridDim.x + blockIdx.x;
        if (mode == 0) partial[bid * 4 + wave] = lsum;
        else atomicAdd(&acc[(bid * 4 + wave) & (NSLOT - 1)], (double)lsum);
    }
}

__global__ void ssim_init(double* acc)
{
    if (threadIdx.x < NSLOT) acc[threadIdx.x] = 0.0;
}

__global__ __launch_bounds__(1024)
void ssim_fin_slots(const float* __restrict__ partial, float* __restrict__ out,
                    int n4, double inv_n)
{
    __shared__ double red[16];
    double s = 0.0;
    const int tid = threadIdx.x;
    for (int i = tid; i < n4; i += 1024) {
        float4 v = ((const float4*)partial)[i];
        s += (double)v.x + (double)v.y + (double)v.z + (double)v.w;
    }
    #pragma unroll
    for (int off = 32; off > 0; off >>= 1)
        s += __shfl_down(s, off, 64);
    if ((tid & 63) == 0) red[tid >> 6] = s;
    __syncthreads();
    if (tid == 0) {
        double tot = 0.0;
        #pragma unroll
        for (int w = 0; w < 16; ++w) tot += red[w];
        out[0] = (float)(1.0 - tot * inv_n);
    }
}

__global__ void ssim_fin_atomic(const double* __restrict__ acc, float* __restrict__ out,
                                double inv_n)
{
    if (threadIdx.x == 0) {
        double s = 0.0;
        for (int i = 0; i < NSLOT; ++i) s += acc[i];
        out[0] = (float)(1.0 - s * inv_n);
    }
}

extern "C" void kernel_launch(void* const* d_in, const int* in_sizes, int n_in,
                              void* d_out, int out_size, void* d_ws, size_t ws_size,
                              hipStream_t stream)
{
    const float* pred = (const float*)d_in[0];
    const float* targ = (const float*)d_in[1];
    float* out = (float*)d_out;

    const long long total = (long long)in_sizes[0];       // 16*3*512*512
    const int n_img = (int)(total / (IMG_H * IMG_W));     // 48 planes
    dim3 grid(IMG_W / 32, IMG_H / 32, n_img);
    const int nblk = grid.x * grid.y * grid.z;
    const int nslots = nblk * 4;
    const double inv_n = 1.0 / (double)total;

    if (ws_size >= (size_t)nslots * sizeof(float)) {
        float* partial = (float*)d_ws;
        hipLaunchKernelGGL(ssim_main, grid, dim3(256), 0, stream,
                           pred, targ, partial, (double*)nullptr, 0);
        hipLaunchKernelGGL(ssim_fin_slots, dim3(1), dim3(1024), 0, stream,
                           partial, out, nslots / 4, inv_n);
    } else {
        double* acc = (double*)d_ws;
        hipLaunchKernelGGL(ssim_init, dim3(1), dim3(64), 0, stream, acc);
        hipLaunchKernelGGL(ssim_main, grid, dim3(256), 0, stream,
                           pred, targ, (float*)nullptr, acc, 1);
        hipLaunchKernelGGL(ssim_fin_atomic, dim3(1), dim3(1), 0, stream,
                           acc, out, inv_n);
    }
}